// Round 5
// baseline (679.635 us; speedup 1.0000x reference)
//
#include <hip/hip_runtime.h>

typedef short bf8 __attribute__((ext_vector_type(8)));
typedef float f4 __attribute__((ext_vector_type(4)));
typedef float float4v __attribute__((ext_vector_type(4)));

#define DEV static __device__ __forceinline__

DEV short f2bf(float f) {
  unsigned u = __float_as_uint(f);
  u += 0x7FFF + ((u >> 16) & 1);   // RNE f32 -> bf16
  return (short)(u >> 16);
}

DEV f4 mfma16(bf8 a, bf8 b, f4 c) {
  return __builtin_amdgcn_mfma_f32_16x16x32_bf16(a, b, c, 0, 0, 0);
}

// ---------------- workspace layout (units: shorts / bf16 elems) ----------------
#define QP_OFF 0
#define QP_SZ  (4*16*1024*64)
#define KP_OFF (QP_OFF + QP_SZ)
#define KP_SZ  (4*16*1088*64)
#define VT_OFF (KP_OFF + KP_SZ)
#define VT_SZ  (4*16*1088*64)
#define WO_OFF (VT_OFF + VT_SZ)
#define WO_SZ  (1024*1024)
#define AO_OFF (WO_OFF + WO_SZ)

// =============== Phase 1a: per-head 64x64 projections (Q,K,V) ===============
__global__ __launch_bounds__(256) void k_proj(
    const float* __restrict__ vals, const float* __restrict__ keys,
    const float* __restrict__ qrys,
    const float* __restrict__ Wv, const float* __restrict__ Wk,
    const float* __restrict__ Wq,
    short* __restrict__ ws)
{
  short* Qp = ws + QP_OFF;
  short* Kp = ws + KP_OFF;
  short* Vt = ws + VT_OFF;
  __shared__ float ldsT[4][16][68];

  const int tid = threadIdx.x, wave = tid >> 6, lane = tid & 63;
  const int l16 = lane & 15, lh = lane >> 4;
  const int gbase = (blockIdx.x * 4 + wave) * 4;   // 4 groups per wave
  const int type = gbase >> 12;                    // uniform per block
  const f4 fzero = {0.f, 0.f, 0.f, 0.f};

  const float* in;
  const float* W;
  if (type == 0)      { in = qrys; W = Wq; }
  else if (type == 1) { in = keys; W = Wk; }
  else                { in = vals; W = Wv; }

  bf8 wf[4][2];
#pragma unroll
  for (int ct = 0; ct < 4; ++ct)
#pragma unroll
    for (int kh = 0; kh < 2; ++kh) {
      const float4v* p = (const float4v*)(W + (ct*16 + l16)*64 + kh*32 + lh*8);
      float4v w0 = p[0], w1 = p[1];
      bf8 t;
#pragma unroll
      for (int j = 0; j < 4; ++j) { t[j] = f2bf(w0[j]); t[4+j] = f2bf(w1[j]); }
      wf[ct][kh] = t;
    }

  for (int i = 0; i < 4; ++i) {
    const int gi = (gbase + i) & 4095;
    if (type < 2) {
      const int n = gi >> 10, l = gi & 1023;
      const float4v* a4 = (const float4v*)(in + gi*1024 + l16*64 + lh*8);
      float4v v0 = a4[0], v1 = a4[1], v2 = a4[8], v3 = a4[9];
      bf8 a0, a1;
#pragma unroll
      for (int j = 0; j < 4; ++j) {
        a0[j] = f2bf(v0[j]); a0[4+j] = f2bf(v1[j]);
        a1[j] = f2bf(v2[j]); a1[4+j] = f2bf(v3[j]);
      }
#pragma unroll
      for (int ct = 0; ct < 4; ++ct) {
        f4 e = fzero;
        e = mfma16(a0, wf[ct][0], e);
        e = mfma16(a1, wf[ct][1], e);
#pragma unroll
        for (int jj = 0; jj < 4; ++jj) {
          const int h = lh*4 + jj, c = ct*16 + l16;
          if (type == 0) Qp[((n*16 + h)*1024 + l)*64 + c] = f2bf(e[jj]);
          else           Kp[((n*16 + h)*1088 + l)*64 + c] = f2bf(e[jj]);
        }
      }
    } else {
      const int nh = gi >> 6, lt = (gi & 63) * 16;
      const int n = nh >> 4, h = nh & 15;
      const float4v* a4 = (const float4v*)(in + (n*1024 + lt + l16)*1024 + h*64 + lh*8);
      float4v v0 = a4[0], v1 = a4[1], v2 = a4[8], v3 = a4[9];
      bf8 a0, a1;
#pragma unroll
      for (int j = 0; j < 4; ++j) {
        a0[j] = f2bf(v0[j]); a0[4+j] = f2bf(v1[j]);
        a1[j] = f2bf(v2[j]); a1[4+j] = f2bf(v3[j]);
      }
#pragma unroll
      for (int ct = 0; ct < 4; ++ct) {
        f4 e = fzero;
        e = mfma16(a0, wf[ct][0], e);
        e = mfma16(a1, wf[ct][1], e);
#pragma unroll
        for (int jj = 0; jj < 4; ++jj)
          ldsT[wave][lh*4 + jj][ct*16 + l16] = e[jj];
      }
      // ldsT[wave] is wave-private: in-wave LDS ordering via waitcnt, no barrier
      short* vb = Vt + (nh*64 + lane)*1088 + lt;
      bf8 t0, t1;
#pragma unroll
      for (int j = 0; j < 8; ++j) {
        t0[j] = f2bf(ldsT[wave][j][lane]);
        t1[j] = f2bf(ldsT[wave][8 + j][lane]);
      }
      *(bf8*)vb = t0;
      *(bf8*)(vb + 8) = t1;
    }
  }
}

// =============== Phase 1b: persistent rows, zero pads, Wo -> bf16 ===============
__global__ __launch_bounds__(256) void k_fill(
    const float* __restrict__ Wo, const float* __restrict__ pkeys,
    const float* __restrict__ pvals, short* __restrict__ ws)
{
  short* Kp = ws + KP_OFF;
  short* Vt = ws + VT_OFF;
  short* Wo_bf = ws + WO_OFF;
  const int NT = 1048576 + 65536 + 196608 + 65536 + 196608;
  for (int i = blockIdx.x*blockDim.x + threadIdx.x; i < NT; i += gridDim.x*blockDim.x) {
    int x = i;
    if (x < 1048576) { Wo_bf[x] = f2bf(Wo[x]); continue; }
    x -= 1048576;
    if (x < 65536) {
      const int d = x & 63, p = (x >> 6) & 15, nh = x >> 10;
      Kp[(nh*1088 + 1024 + p)*64 + d] = f2bf(pkeys[p*64 + d]);
      continue;
    }
    x -= 65536;
    if (x < 196608) {
      const int d = x & 63, r = x >> 6, z = r % 48, nh = r / 48;
      Kp[(nh*1088 + 1040 + z)*64 + d] = 0;
      continue;
    }
    x -= 196608;
    if (x < 65536) {
      const int d = x & 63, p = (x >> 6) & 15, nh = x >> 10;
      Vt[(nh*64 + d)*1088 + 1024 + p] = f2bf(pvals[p*64 + d]);
      continue;
    }
    x -= 65536;
    {
      const int d = x & 63, r = x >> 6, z = r % 48, nh = r / 48;
      Vt[(nh*64 + d)*1088 + 1040 + z] = 0;
    }
  }
}

// =============== Phase 2: fused talking-heads attention ===============
// grid = n(4) x qtile(128, 8 rows each); block = 16 waves (1024 thr), 2 blocks/CU.
// QK/PV: wave = head. Mix/exp: wave w -> q-row w&7, k-half w>>3.
// Double-buffered ldsE/ldsA -> ONE barrier per k-step; segment = PV+mix+QK.
#define HP 16
#define EN (8*64*HP + 16)     // 8208 shorts per E buffer (16-short zero tail)
#define KP2 72
#define AN (16*8*KP2)         // 9216 shorts per A buffer
__global__ __launch_bounds__(1024, 8) void k_attn(
    const int* __restrict__ mask, const float* __restrict__ th_pre,
    const float* __restrict__ th_post, short* ws)
{
  const short* Qp = ws + QP_OFF;
  const short* Kp = ws + KP_OFF;
  const short* Vt = ws + VT_OFF;
  short* AO = ws + AO_OFF;

  __shared__ __align__(16) short ldsE[2][EN];   // [elem=(q,k)][h]
  __shared__ __align__(16) short ldsA[2][AN];   // [o][q][k]
  __shared__ float Zbuf[2][8][16];              // [khalf][q][o]

  const int tid = threadIdx.x, wave = tid >> 6, lane = tid & 63;
  const int l16 = lane & 15, lh = lane >> 4;
  const int n = blockIdx.x >> 7, qt = blockIdx.x & 127, q0 = qt * 8;
  const f4 fzero = {0.f, 0.f, 0.f, 0.f};

  // zero the E tails once (lh=3 B-frag overrun on the last elem lands here)
  if (tid < 16) { ldsE[0][8*64*HP + tid] = 0; ldsE[1][8*64*HP + tid] = 0; }

  // talking-heads A-fragments, zero-padded to K=32 (lanes lh>=2 hold zeros)
  bf8 thA[2];
  {
    bf8 z;
#pragma unroll
    for (int j = 0; j < 8; ++j) z[j] = 0;
    thA[0] = z; thA[1] = z;
    if (lh < 2) {
      const float* r0 = th_pre  + l16*16 + lh*8;
      const float* r1 = th_post + l16*16 + lh*8;
      bf8 t0, t1;
#pragma unroll
      for (int j = 0; j < 8; ++j) { t0[j] = f2bf(r0[j]); t1[j] = f2bf(r1[j]); }
      thA[0] = t0; thA[1] = t1;
    }
  }
  // mixed ALiBi slopes for o = lh*4+jj
  float mslope[4];
#pragma unroll
  for (int jj = 0; jj < 4; ++jj) {
    const int o = lh*4 + jj;
    float s = 0.f;
    for (int h = 0; h < 16; ++h) s += th_pre[o*16 + h] * exp2f(-(float)(h + 1));
    mslope[jj] = s;
  }

  const int q = wave & 7, kh2 = wave >> 3, ig = q0 + q;

  // Q fragments for head = wave; A rows 8..15 duplicate rows 0..7 (l16&7)
  bf8 qf[2];
#pragma unroll
  for (int kh = 0; kh < 2; ++kh)
    qf[kh] = *(const bf8*)(Qp + ((n*16 + wave)*1024 + q0 + (l16 & 7))*64 + kh*32 + lh*8);

  const int* maskn = mask + n*1024;

  // QK for head=wave, 64 k-cols at K0, into ldsE[EB]; only q<8 rows stored
#define QK_STAGE(EB, K0) { \
    const short* Kb = Kp + ((n*16 + wave)*1088 + (K0) + l16)*64 + lh*8; \
    _Pragma("unroll") \
    for (int kt = 0; kt < 4; ++kt) { \
      f4 e = fzero; \
      e = mfma16(qf[0], *(const bf8*)(Kb + kt*1024), e); \
      e = mfma16(qf[1], *(const bf8*)(Kb + kt*1024 + 32), e); \
      if (lh < 2) { \
        _Pragma("unroll") \
        for (int jj = 0; jj < 4; ++jj) \
          ldsE[EB][((lh*4 + jj)*64 + kt*16 + l16)*HP + wave] = f2bf(e[jj]); \
      } \
    } }

#define PV_STEP(AB, K0) { \
    const short* Vb = Vt + (n*16 + wave)*64*1088 + (K0); \
    _Pragma("unroll") \
    for (int kkh = 0; kkh < 2; ++kkh) { \
      bf8 af = *(const bf8*)(&ldsA[AB][(wave*8 + (l16 & 7))*KP2 + kkh*32 + lh*8]); \
      _Pragma("unroll") \
      for (int dt = 0; dt < 4; ++dt) { \
        bf8 vf = *(const bf8*)(Vb + (dt*16 + l16)*1088 + kkh*32 + lh*8); \
        acc[dt] = mfma16(af, vf, acc[dt]); \
      } \
    } }

  // ---------------- sweep 1: Z ----------------
  QK_STAGE(0, 0);
  __syncthreads();
  float Zp[4] = {0.f, 0.f, 0.f, 0.f};
  for (int kb = 0; kb < 17; ++kb) {
    const int cur = kb & 1;
    if (kb < 16) QK_STAGE(cur ^ 1, (kb + 1)*64);
    const int k0 = kb*64;
#pragma unroll
    for (int ksi = 0; ksi < 2; ++ksi) {
      const int ks = kh2*2 + ksi;
      const int elem = q*64 + ks*16 + l16;
      bf8 Bf = *(const bf8*)(&ldsE[cur][elem*HP + lh*8]);
      f4 s = mfma16(thA[0], Bf, fzero);
      const int kg = k0 + ks*16 + l16;
      float ad = 0.f; bool dead;
      if (kg < 1024) { dead = (maskn[kg] == 0); ad = fabsf((float)(ig - kg)); }
      else           { dead = (kg >= 1040); }
#pragma unroll
      for (int jj = 0; jj < 4; ++jj) {
        float v = s[jj] - ad * mslope[jj];
        v = dead ? -1e4f : v;
        Zp[jj] += __expf(v * 0.03125f);
      }
    }
    __syncthreads();
  }
  // reduce over 16 k-lanes, then combine the two k-halves via Zbuf
#pragma unroll
  for (int jj = 0; jj < 4; ++jj) {
    float z = Zp[jj];
    z += __shfl_xor(z, 1); z += __shfl_xor(z, 2);
    z += __shfl_xor(z, 4); z += __shfl_xor(z, 8);
    Zp[jj] = z;
  }
  if (l16 == 0) {
#pragma unroll
    for (int jj = 0; jj < 4; ++jj) Zbuf[kh2][q][lh*4 + jj] = Zp[jj];
  }
  __syncthreads();
  float invZ[4];
#pragma unroll
  for (int jj = 0; jj < 4; ++jj)
    invZ[jj] = 1.f / (Zbuf[0][q][lh*4 + jj] + Zbuf[1][q][lh*4 + jj]);

  // ---------------- sweep 2: normalize, th_post mix, PV ----------------
  f4 acc[4];
#pragma unroll
  for (int a = 0; a < 4; ++a) acc[a] = fzero;

  QK_STAGE(0, 0);
  __syncthreads();
  for (int kb = 0; kb < 17; ++kb) {
    const int cur = kb & 1;
    if (kb < 16) QK_STAGE(cur ^ 1, (kb + 1)*64);
    if (kb > 0)  PV_STEP(cur ^ 1, (kb - 1)*64);
    const int k0 = kb*64;
#pragma unroll
    for (int ksi = 0; ksi < 2; ++ksi) {
      const int ks = kh2*2 + ksi;
      const int elem = q*64 + ks*16 + l16;
      bf8 Bf = *(const bf8*)(&ldsE[cur][elem*HP + lh*8]);
      f4 s = mfma16(thA[0], Bf, fzero);
      const int kg = k0 + ks*16 + l16;
      float ad = 0.f; bool dead;
      if (kg < 1024) { dead = (maskn[kg] == 0); ad = fabsf((float)(ig - kg)); }
      else           { dead = (kg >= 1040); }
      float p[4];
#pragma unroll
      for (int jj = 0; jj < 4; ++jj) {
        float v = s[jj] - ad * mslope[jj];
        v = dead ? -1e4f : v;
        p[jj] = __expf(v * 0.03125f) * invZ[jj];
      }
      // build mix2 B-frag: lane needs p over o' = lh*8..lh*8+7 for its k col
      const int pk0 = ((int)(unsigned short)f2bf(p[1]) << 16) | (unsigned short)f2bf(p[0]);
      const int pk1 = ((int)(unsigned short)f2bf(p[3]) << 16) | (unsigned short)f2bf(p[2]);
      const int s0 = (lh*2)*16 + l16, s1 = (lh*2 + 1)*16 + l16;
      union { int w[4]; bf8 v; } mb;
      mb.w[0] = __shfl(pk0, s0); mb.w[1] = __shfl(pk1, s0);
      mb.w[2] = __shfl(pk0, s1); mb.w[3] = __shfl(pk1, s1);
      f4 a = mfma16(thA[1], mb.v, fzero);
#pragma unroll
      for (int jj = 0; jj < 4; ++jj)
        ldsA[cur][((lh*4 + jj)*8 + q)*KP2 + ks*16 + l16] = f2bf(a[jj]);
    }
    __syncthreads();
  }
  PV_STEP(0, 1024);   // kb=16's A tile (buffer 16&1=0)

  // store attention output [n][q][o*64+d] bf16, o = wave, q rows 0..7 (lh<2)
  if (lh < 2) {
#pragma unroll
    for (int dt = 0; dt < 4; ++dt)
#pragma unroll
      for (int jj = 0; jj < 4; ++jj)
        AO[(n*1024 + q0 + lh*4 + jj)*1024 + wave*64 + dt*16 + l16] =
            f2bf(acc[dt][jj]);
  }
}

// =============== Phase 3: out = AO @ Wo^T + bo (f32 out) ===============
__global__ __launch_bounds__(256) void k_out(
    const short* __restrict__ ws, const float* __restrict__ bo,
    float* __restrict__ out)
{
  const short* A  = ws + AO_OFF;
  const short* Wb = ws + WO_OFF;
  const int tid = threadIdx.x, wave = tid >> 6, lane = tid & 63;
  const int l16 = lane & 15, lh = lane >> 4;
  const int r0 = blockIdx.x*64 + wave*16, c0 = blockIdx.y*64;
  const f4 fzero = {0.f, 0.f, 0.f, 0.f};
  f4 acc[4];
#pragma unroll
  for (int ct = 0; ct < 4; ++ct) acc[ct] = fzero;

  const short* Ar = A  + (r0 + l16)*1024 + lh*8;
  const short* Wr = Wb + (c0 + l16)*1024 + lh*8;
  for (int kk = 0; kk < 1024; kk += 32) {
    bf8 af = *(const bf8*)(Ar + kk);
#pragma unroll
    for (int ct = 0; ct < 4; ++ct) {
      bf8 bf = *(const bf8*)(Wr + ct*16*1024 + kk);
      acc[ct] = mfma16(af, bf, acc[ct]);
    }
  }
#pragma unroll
  for (int ct = 0; ct < 4; ++ct) {
    const int c = c0 + ct*16 + l16;
    const float b = bo[c];
#pragma unroll
    for (int jj = 0; jj < 4; ++jj)
      out[(r0 + lh*4 + jj)*1024 + c] = acc[ct][jj] + b;
  }
}

extern "C" void kernel_launch(void* const* d_in, const int* in_sizes, int n_in,
                              void* d_out, int out_size, void* d_ws, size_t ws_size,
                              hipStream_t stream) {
  const float* vals = (const float*)d_in[0];
  const float* keys = (const float*)d_in[1];
  const float* qrys = (const float*)d_in[2];
  const int*   mask = (const int*)d_in[3];
  const float* Wv   = (const float*)d_in[4];
  const float* Wk   = (const float*)d_in[5];
  const float* Wq   = (const float*)d_in[6];
  const float* Wo   = (const float*)d_in[7];
  const float* bo   = (const float*)d_in[8];
  const float* thp  = (const float*)d_in[9];
  const float* tho  = (const float*)d_in[10];
  const float* pk   = (const float*)d_in[11];
  const float* pv   = (const float*)d_in[12];
  short* ws = (short*)d_ws;
  float* out = (float*)d_out;

  k_proj<<<768, 256, 0, stream>>>(vals, keys, qrys, Wv, Wk, Wq, ws);
  k_fill<<<512, 256, 0, stream>>>(Wo, pk, pv, ws);
  k_attn<<<512, 1024, 0, stream>>>(mask, thp, tho, ws);
  k_out<<<dim3(64, 16), 256, 0, stream>>>(ws, bo, out);
}

// Round 7
// 446.200 us; speedup vs baseline: 1.5232x; 1.5232x over previous
//
#include <hip/hip_runtime.h>

typedef short bf8 __attribute__((ext_vector_type(8)));
typedef short bf4 __attribute__((ext_vector_type(4)));
typedef float f4 __attribute__((ext_vector_type(4)));
typedef float float4v __attribute__((ext_vector_type(4)));

#define DEV static __device__ __forceinline__

DEV short f2bf(float f) {
  unsigned u = __float_as_uint(f);
  u += 0x7FFF + ((u >> 16) & 1);   // RNE f32 -> bf16
  return (short)(u >> 16);
}

DEV f4 mfma16(bf8 a, bf8 b, f4 c) {
  return __builtin_amdgcn_mfma_f32_16x16x32_bf16(a, b, c, 0, 0, 0);
}

// ---------------- workspace layout (units: shorts / bf16 elems) ----------------
#define QP_OFF 0
#define QP_SZ  (4*16*1024*64)
#define KP_OFF (QP_OFF + QP_SZ)
#define KP_SZ  (4*16*1088*64)
#define VT_OFF (KP_OFF + KP_SZ)
#define VT_SZ  (4*16*1088*64)
#define WO_OFF (VT_OFF + VT_SZ)
#define WO_SZ  (1024*1024)
#define AO_OFF (WO_OFF + WO_SZ)

// =============== Phase 1a: per-head 64x64 projections (Q,K,V) ===============
__global__ __launch_bounds__(256) void k_proj(
    const float* __restrict__ vals, const float* __restrict__ keys,
    const float* __restrict__ qrys,
    const float* __restrict__ Wv, const float* __restrict__ Wk,
    const float* __restrict__ Wq,
    short* __restrict__ ws)
{
  short* Qp = ws + QP_OFF;
  short* Kp = ws + KP_OFF;
  short* Vt = ws + VT_OFF;
  __shared__ float ldsT[4][16][68];

  const int tid = threadIdx.x, wave = tid >> 6, lane = tid & 63;
  const int l16 = lane & 15, lh = lane >> 4;
  const int gbase = (blockIdx.x * 4 + wave) * 4;   // 4 groups per wave
  const int type = gbase >> 12;                    // uniform per block
  const f4 fzero = {0.f, 0.f, 0.f, 0.f};

  const float* in;
  const float* W;
  if (type == 0)      { in = qrys; W = Wq; }
  else if (type == 1) { in = keys; W = Wk; }
  else                { in = vals; W = Wv; }

  bf8 wf[4][2];
#pragma unroll
  for (int ct = 0; ct < 4; ++ct)
#pragma unroll
    for (int kh = 0; kh < 2; ++kh) {
      const float4v* p = (const float4v*)(W + (ct*16 + l16)*64 + kh*32 + lh*8);
      float4v w0 = p[0], w1 = p[1];
      bf8 t;
#pragma unroll
      for (int j = 0; j < 4; ++j) { t[j] = f2bf(w0[j]); t[4+j] = f2bf(w1[j]); }
      wf[ct][kh] = t;
    }

  for (int i = 0; i < 4; ++i) {
    const int gi = (gbase + i) & 4095;
    if (type < 2) {
      const int n = gi >> 10, l = gi & 1023;
      const float4v* a4 = (const float4v*)(in + gi*1024 + l16*64 + lh*8);
      float4v v0 = a4[0], v1 = a4[1], v2 = a4[8], v3 = a4[9];
      bf8 a0, a1;
#pragma unroll
      for (int j = 0; j < 4; ++j) {
        a0[j] = f2bf(v0[j]); a0[4+j] = f2bf(v1[j]);
        a1[j] = f2bf(v2[j]); a1[4+j] = f2bf(v3[j]);
      }
#pragma unroll
      for (int ct = 0; ct < 4; ++ct) {
        f4 e = fzero;
        e = mfma16(a0, wf[ct][0], e);
        e = mfma16(a1, wf[ct][1], e);
#pragma unroll
        for (int jj = 0; jj < 4; ++jj) {
          const int h = lh*4 + jj, c = ct*16 + l16;
          if (type == 0) Qp[((n*16 + h)*1024 + l)*64 + c] = f2bf(e[jj]);
          else           Kp[((n*16 + h)*1088 + l)*64 + c] = f2bf(e[jj]);
        }
      }
    } else {
      const int nh = gi >> 6, lt = (gi & 63) * 16;
      const int n = nh >> 4, h = nh & 15;
      const float4v* a4 = (const float4v*)(in + (n*1024 + lt + l16)*1024 + h*64 + lh*8);
      float4v v0 = a4[0], v1 = a4[1], v2 = a4[8], v3 = a4[9];
      bf8 a0, a1;
#pragma unroll
      for (int j = 0; j < 4; ++j) {
        a0[j] = f2bf(v0[j]); a0[4+j] = f2bf(v1[j]);
        a1[j] = f2bf(v2[j]); a1[4+j] = f2bf(v3[j]);
      }
#pragma unroll
      for (int ct = 0; ct < 4; ++ct) {
        f4 e = fzero;
        e = mfma16(a0, wf[ct][0], e);
        e = mfma16(a1, wf[ct][1], e);
#pragma unroll
        for (int jj = 0; jj < 4; ++jj)
          ldsT[wave][lh*4 + jj][ct*16 + l16] = e[jj];
      }
      // ldsT[wave] is wave-private: in-wave LDS ordering via waitcnt, no barrier
      short* vb = Vt + (nh*64 + lane)*1088 + lt;
      bf8 t0, t1;
#pragma unroll
      for (int j = 0; j < 8; ++j) {
        t0[j] = f2bf(ldsT[wave][j][lane]);
        t1[j] = f2bf(ldsT[wave][8 + j][lane]);
      }
      *(bf8*)vb = t0;
      *(bf8*)(vb + 8) = t1;
    }
  }
}

// =============== Phase 1b: persistent rows, zero pads, Wo -> bf16 ===============
__global__ __launch_bounds__(256) void k_fill(
    const float* __restrict__ Wo, const float* __restrict__ pkeys,
    const float* __restrict__ pvals, short* __restrict__ ws)
{
  short* Kp = ws + KP_OFF;
  short* Vt = ws + VT_OFF;
  short* Wo_bf = ws + WO_OFF;
  const int NT = 1048576 + 65536 + 196608 + 65536 + 196608;
  for (int i = blockIdx.x*blockDim.x + threadIdx.x; i < NT; i += gridDim.x*blockDim.x) {
    int x = i;
    if (x < 1048576) { Wo_bf[x] = f2bf(Wo[x]); continue; }
    x -= 1048576;
    if (x < 65536) {
      const int d = x & 63, p = (x >> 6) & 15, nh = x >> 10;
      Kp[(nh*1088 + 1024 + p)*64 + d] = f2bf(pkeys[p*64 + d]);
      continue;
    }
    x -= 65536;
    if (x < 196608) {
      const int d = x & 63, r = x >> 6, z = r % 48, nh = r / 48;
      Kp[(nh*1088 + 1040 + z)*64 + d] = 0;
      continue;
    }
    x -= 196608;
    if (x < 65536) {
      const int d = x & 63, p = (x >> 6) & 15, nh = x >> 10;
      Vt[(nh*64 + d)*1088 + 1024 + p] = f2bf(pvals[p*64 + d]);
      continue;
    }
    x -= 65536;
    {
      const int d = x & 63, r = x >> 6, z = r % 48, nh = r / 48;
      Vt[(nh*64 + d)*1088 + 1040 + z] = 0;
    }
  }
}

// =============== Phase 2: fused talking-heads attention ===============
// grid = n(4) x qtile(64 of 16 rows); block = 16 waves (1024 thr), 1 block/CU.
// QK/PV: wave = head. Mix/exp: wave = q-row. Double-buffered ldsE AND ldsA ->
// ONE barrier per k-step; segment = QK(kb+1) + PV(kb-1) + mix(kb).
#define HP 20
#define EN (16*64*HP + 16)     // 20496 shorts per E buffer
#define KP2 72
#define AN (16*16*KP2)         // 18432 shorts per A buffer
__global__ __launch_bounds__(1024, 4) void k_attn(
    const int* __restrict__ mask, const float* __restrict__ th_pre,
    const float* __restrict__ th_post, short* ws)
{
  const short* Qp = ws + QP_OFF;
  const short* Kp = ws + KP_OFF;
  const short* Vt = ws + VT_OFF;
  short* AO = ws + AO_OFF;

  __shared__ __align__(16) short ldsE[2][EN];   // [elem=(q,k)][h], pitch 20
  __shared__ __align__(16) short ldsA[2][AN];   // [o][q][k], pitch 72

  const int tid = threadIdx.x, wave = tid >> 6, lane = tid & 63;
  const int l16 = lane & 15, lh = lane >> 4;
  const int n = blockIdx.x >> 6, qt = blockIdx.x & 63, q0 = qt * 16;
  const f4 fzero = {0.f, 0.f, 0.f, 0.f};

  // Zero both E buffers ONCE (b128 stores): pitch slots 16..19 + tail are read
  // by the mix B-frags (k=16..31, zero A-coeff) and must be non-NaN.
  {
    bf8 z8;
#pragma unroll
    for (int j = 0; j < 8; ++j) z8[j] = 0;
    bf8* e8 = (bf8*)ldsE;
    for (int i = tid; i < 2*EN/8; i += 1024) e8[i] = z8;
  }

  // talking-heads A-fragments, zero-padded to K=32 (lanes lh>=2 hold zeros)
  bf8 thA[2];
  {
    bf8 z;
#pragma unroll
    for (int j = 0; j < 8; ++j) z[j] = 0;
    thA[0] = z; thA[1] = z;
    if (lh < 2) {
      const float* r0 = th_pre  + l16*16 + lh*8;
      const float* r1 = th_post + l16*16 + lh*8;
      bf8 t0, t1;
#pragma unroll
      for (int j = 0; j < 8; ++j) { t0[j] = f2bf(r0[j]); t1[j] = f2bf(r1[j]); }
      thA[0] = t0; thA[1] = t1;
    }
  }
  // folded scale: exp(v/32) = exp2(v*C1)
  const float C1 = 0.04508422f;   // log2(e)/32
  float ms2[4];
#pragma unroll
  for (int jj = 0; jj < 4; ++jj) {
    const int o = lh*4 + jj;
    float s = 0.f;
    for (int h = 0; h < 16; ++h) s += th_pre[o*16 + h] * exp2f(-(float)(h + 1));
    ms2[jj] = s * C1;
  }

  const int qr = wave, ig = q0 + qr;   // mix-phase q-row

  // Q fragments for head = wave (16 q-rows of this tile)
  bf8 qf[2];
#pragma unroll
  for (int kh = 0; kh < 2; ++kh)
    qf[kh] = *(const bf8*)(Qp + ((n*16 + wave)*1024 + q0 + l16)*64 + kh*32 + lh*8);

  const int* maskn = mask + n*1024;

  // QK for head=wave, 64 k-cols at K0, into ldsE[EB]
#define QK_STAGE(EB, K0) { \
    const short* Kb = Kp + ((n*16 + wave)*1088 + (K0) + l16)*64 + lh*8; \
    _Pragma("unroll") \
    for (int kt = 0; kt < 4; ++kt) { \
      f4 e = fzero; \
      e = mfma16(qf[0], *(const bf8*)(Kb + kt*1024), e); \
      e = mfma16(qf[1], *(const bf8*)(Kb + kt*1024 + 32), e); \
      _Pragma("unroll") \
      for (int jj = 0; jj < 4; ++jj) \
        ldsE[EB][((lh*4 + jj)*64 + kt*16 + l16)*HP + wave] = f2bf(e[jj]); \
    } }

  // read mix B-frag (h-dim) at elem from ldsE[EB]: two b64 reads (pitch 20)
#define E_READ(EB, elem, BF) { \
    const short* ep = &ldsE[EB][(elem)*HP + lh*8]; \
    bf4 b0 = *(const bf4*)ep, b1 = *(const bf4*)(ep + 4); \
    _Pragma("unroll") \
    for (int j = 0; j < 4; ++j) { BF[j] = b0[j]; BF[4+j] = b1[j]; } }

#define PV_STEP(AB, K0) { \
    const short* Vb = Vt + (n*16 + wave)*64*1088 + (K0); \
    _Pragma("unroll") \
    for (int kkh = 0; kkh < 2; ++kkh) { \
      bf8 af = *(const bf8*)(&ldsA[AB][(wave*16 + l16)*KP2 + kkh*32 + lh*8]); \
      _Pragma("unroll") \
      for (int dt = 0; dt < 4; ++dt) { \
        bf8 vf = *(const bf8*)(Vb + (dt*16 + l16)*1088 + kkh*32 + lh*8); \
        acc[dt] = mfma16(af, vf, acc[dt]); \
      } \
    } }

  __syncthreads();   // after E zero-init

  // ---------------- sweep 1: Z ----------------
  QK_STAGE(0, 0);
  __syncthreads();
  float Zp[4] = {0.f, 0.f, 0.f, 0.f};
  for (int kb = 0; kb < 17; ++kb) {
    const int cur = kb & 1;
    if (kb < 16) QK_STAGE(cur ^ 1, (kb + 1)*64);
    const int k0 = kb*64;
#pragma unroll
    for (int ks = 0; ks < 4; ++ks) {
      const int elem = qr*64 + ks*16 + l16;
      bf8 Bf; E_READ(cur, elem, Bf);
      f4 s = mfma16(thA[0], Bf, fzero);
      const int kg = k0 + ks*16 + l16;
      float ad = 0.f; bool dead;
      if (kg < 1024) { dead = (maskn[kg] == 0); ad = fabsf((float)(ig - kg)); }
      else           { dead = (kg >= 1040); }
#pragma unroll
      for (int jj = 0; jj < 4; ++jj) {
        float v = s[jj]*C1 - ad*ms2[jj];
        v = dead ? -512.f : v;
        Zp[jj] += exp2f(v);
      }
    }
    __syncthreads();
  }
  // reduce over the 16 k-col lanes (per lh group)
  float invZ[4];
#pragma unroll
  for (int jj = 0; jj < 4; ++jj) {
    float z = Zp[jj];
    z += __shfl_xor(z, 1); z += __shfl_xor(z, 2);
    z += __shfl_xor(z, 4); z += __shfl_xor(z, 8);
    invZ[jj] = 1.f / z;
  }

  // ---------------- sweep 2: normalize, th_post mix, PV ----------------
  f4 acc[4];
#pragma unroll
  for (int a = 0; a < 4; ++a) acc[a] = fzero;

  QK_STAGE(0, 0);
  __syncthreads();
  for (int kb = 0; kb < 17; ++kb) {
    const int cur = kb & 1;
    if (kb < 16) QK_STAGE(cur ^ 1, (kb + 1)*64);
    if (kb > 0)  PV_STEP(cur ^ 1, (kb - 1)*64);
    const int k0 = kb*64;
#pragma unroll
    for (int ks = 0; ks < 4; ++ks) {
      const int elem = qr*64 + ks*16 + l16;
      bf8 Bf; E_READ(cur, elem, Bf);
      f4 s = mfma16(thA[0], Bf, fzero);
      const int kg = k0 + ks*16 + l16;
      float ad = 0.f; bool dead;
      if (kg < 1024) { dead = (maskn[kg] == 0); ad = fabsf((float)(ig - kg)); }
      else           { dead = (kg >= 1040); }
      float p[4];
#pragma unroll
      for (int jj = 0; jj < 4; ++jj) {
        float v = s[jj]*C1 - ad*ms2[jj];
        v = dead ? -512.f : v;
        p[jj] = exp2f(v) * invZ[jj];
      }
      // build mix2 B-frag: lane needs p over o' = lh*8..lh*8+7 for its k col
      const int pk0 = ((int)(unsigned short)f2bf(p[1]) << 16) | (unsigned short)f2bf(p[0]);
      const int pk1 = ((int)(unsigned short)f2bf(p[3]) << 16) | (unsigned short)f2bf(p[2]);
      const int s0 = (lh*2)*16 + l16, s1 = (lh*2 + 1)*16 + l16;
      union { int w[4]; bf8 v; } mb;
      mb.w[0] = __shfl(pk0, s0); mb.w[1] = __shfl(pk1, s0);
      mb.w[2] = __shfl(pk0, s1); mb.w[3] = __shfl(pk1, s1);
      f4 a = mfma16(thA[1], mb.v, fzero);
#pragma unroll
      for (int jj = 0; jj < 4; ++jj)
        ldsA[cur][((lh*4 + jj)*16 + qr)*KP2 + ks*16 + l16] = f2bf(a[jj]);
    }
    __syncthreads();
  }
  PV_STEP(0, 1024);   // kb=16's A tile (cur=0)

  // store attention output [n][q][o*64+d] bf16, o = wave
#pragma unroll
  for (int dt = 0; dt < 4; ++dt)
#pragma unroll
    for (int jj = 0; jj < 4; ++jj)
      AO[(n*1024 + q0 + lh*4 + jj)*1024 + wave*64 + dt*16 + l16] =
          f2bf(acc[dt][jj]);
}

// =============== Phase 3: out = AO @ Wo^T + bo (f32 out) ===============
__global__ __launch_bounds__(256) void k_out(
    const short* __restrict__ ws, const float* __restrict__ bo,
    float* __restrict__ out)
{
  const short* A  = ws + AO_OFF;
  const short* Wb = ws + WO_OFF;
  const int tid = threadIdx.x, wave = tid >> 6, lane = tid & 63;
  const int l16 = lane & 15, lh = lane >> 4;
  const int r0 = blockIdx.x*64 + wave*16, c0 = blockIdx.y*64;
  const f4 fzero = {0.f, 0.f, 0.f, 0.f};
  f4 acc[4];
#pragma unroll
  for (int ct = 0; ct < 4; ++ct) acc[ct] = fzero;

  const short* Ar = A  + (r0 + l16)*1024 + lh*8;
  const short* Wr = Wb + (c0 + l16)*1024 + lh*8;
  for (int kk = 0; kk < 1024; kk += 32) {
    bf8 af = *(const bf8*)(Ar + kk);
#pragma unroll
    for (int ct = 0; ct < 4; ++ct) {
      bf8 bf = *(const bf8*)(Wr + ct*16*1024 + kk);
      acc[ct] = mfma16(af, bf, acc[ct]);
    }
  }
#pragma unroll
  for (int ct = 0; ct < 4; ++ct) {
    const int c = c0 + ct*16 + l16;
    const float b = bo[c];
#pragma unroll
    for (int jj = 0; jj < 4; ++jj)
      out[(r0 + lh*4 + jj)*1024 + c] = acc[ct][jj] + b;
  }
}

extern "C" void kernel_launch(void* const* d_in, const int* in_sizes, int n_in,
                              void* d_out, int out_size, void* d_ws, size_t ws_size,
                              hipStream_t stream) {
  const float* vals = (const float*)d_in[0];
  const float* keys = (const float*)d_in[1];
  const float* qrys = (const float*)d_in[2];
  const int*   mask = (const int*)d_in[3];
  const float* Wv   = (const float*)d_in[4];
  const float* Wk   = (const float*)d_in[5];
  const float* Wq   = (const float*)d_in[6];
  const float* Wo   = (const float*)d_in[7];
  const float* bo   = (const float*)d_in[8];
  const float* thp  = (const float*)d_in[9];
  const float* tho  = (const float*)d_in[10];
  const float* pk   = (const float*)d_in[11];
  const float* pv   = (const float*)d_in[12];
  short* ws = (short*)d_ws;
  float* out = (float*)d_out;

  k_proj<<<768, 256, 0, stream>>>(vals, keys, qrys, Wv, Wk, Wq, ws);
  k_fill<<<512, 256, 0, stream>>>(Wo, pk, pv, ws);
  k_attn<<<256, 1024, 0, stream>>>(mask, thp, tho, ws);
  k_out<<<dim3(64, 16), 256, 0, stream>>>(ws, bo, out);
}